// Round 1
// baseline (233.952 us; speedup 1.0000x reference)
//
#include <hip/hip_runtime.h>

#define NN 1024
#define KK 32
#define CZ 128
#define CS 384
#define CG 16

__device__ __forceinline__ float sigmoidf_(float x) { return 1.0f / (1.0f + __expf(-x)); }

__launch_bounds__(256, 2)
__global__ void ntmu_kernel(
    const float* __restrict__ nf,    // [N,384]
    const float* __restrict__ ntr,   // [N,3]
    const float* __restrict__ efeat, // [E,128]
    const int*   __restrict__ eidx,  // [2,E]
    const float* __restrict__ W_nl, const float* __restrict__ b_nl,
    const float* __restrict__ W_nr, const float* __restrict__ b_nr,
    const float* __restrict__ ln_g, const float* __restrict__ ln_b,
    const float* __restrict__ W_ep, const float* __restrict__ b_ep,
    const float* __restrict__ W_eg, const float* __restrict__ b_eg,
    const float* __restrict__ W_dg, const float* __restrict__ b_dg,
    const float* __restrict__ W_dp, const float* __restrict__ b_dp,
    const float* __restrict__ lno_g, const float* __restrict__ lno_b,
    const float* __restrict__ W_lo, const float* __restrict__ b_lo,
    const float* __restrict__ W_og, const float* __restrict__ b_og,
    float* __restrict__ out)
{
    const int n    = blockIdx.x;
    const int tid  = threadIdx.x;
    const int lane = tid & 63;
    const int wave = tid >> 6;
    const int ebase = n * KK;

    __shared__ float s_e2[KK][CZ];     // 16 KB
    __shared__ float s_og[KK][CZ];     // 16 KB
    __shared__ float s_t[KK][4];
    __shared__ float s_gate3[CZ];
    __shared__ float s_nl[CG];
    __shared__ float s_nr[CG];
    __shared__ float s_pp[2][CZ];
    // time-shared arena: phase B: ef[32][128]; phase C: taps[1024][8] + r0[1024]; phase D: upd[32][128]
    __shared__ __align__(16) float s_arena[KK*KK*8 + KK*KK]; // 36 KB

    float*  s_ef    = s_arena;                       // [32*128]
    float4* s_taps4 = reinterpret_cast<float4*>(s_arena);  // [1024][2]
    int*    s_r0    = reinterpret_cast<int*>(s_arena + KK*KK*8); // [1024]
    float*  s_upd   = s_arena;                       // [32*128]

    // ---------------- Phase A0: gather destination coordinates ----------------
    if (tid < KK) {
        int d = eidx[NN*KK + ebase + tid];
        s_t[tid][0] = ntr[d*3 + 0];
        s_t[tid][1] = ntr[d*3 + 1];
        s_t[tid][2] = ntr[d*3 + 2];
    }

    // ---------------- Phase A1: nl, nr (node projections, 16 each) ------------
    if (wave < 2) {
        const float* W  = (wave == 0) ? W_nl : W_nr;
        const float* bb = (wave == 0) ? b_nl : b_nr;
        int g = lane >> 2, q = lane & 3;
        const float* x = nf + n * CS;
        float s = 0.f;
        int c0 = q * 96;
        for (int c = c0; c < c0 + 96; ++c) s = fmaf(x[c], W[c*CG + g], s);
        s += __shfl_xor(s, 1);
        s += __shfl_xor(s, 2);
        if (q == 0) {
            if (wave == 0) s_nl[g] = s + bb[g];
            else           s_nr[g] = s + bb[g];
        }
    }
    __syncthreads();

    // ---------------- Phase A2: gate3 = sigmoid(outer(nl,nr) @ W_dg + b_dg) ---
    {
        int z = tid & 127, h = tid >> 7;
        float p = 0.f;
        for (int a = h*8; a < h*8 + 8; ++a) {
            float nla = s_nl[a];
            #pragma unroll
            for (int b = 0; b < 16; ++b) {
                p = fmaf(nla * s_nr[b], W_dg[(a*16 + b)*CZ + z], p);
            }
        }
        s_pp[h][z] = p;
    }
    __syncthreads();
    if (tid < CZ) {
        s_gate3[tid] = sigmoidf_(s_pp[0][tid] + s_pp[1][tid] + b_dg[tid]);
    }

    // ---------------- Phase B1: LayerNorm of edge features --------------------
    {
        float g0 = ln_g[lane], g1 = ln_g[lane + 64];
        float bb0 = ln_b[lane], bb1 = ln_b[lane + 64];
        for (int it = 0; it < 8; ++it) {
            int j = it*4 + wave;
            const float* row = efeat + (ebase + j) * CZ;
            float x0 = row[lane], x1 = row[lane + 64];
            float s = x0 + x1, s2 = x0*x0 + x1*x1;
            #pragma unroll
            for (int o = 1; o < 64; o <<= 1) { s += __shfl_xor(s, o); s2 += __shfl_xor(s2, o); }
            float mu  = s * (1.f/128.f);
            float var = s2 * (1.f/128.f) - mu*mu;
            float inv = rsqrtf(var + 1e-5f);
            s_ef[j*CZ + lane]      = (x0 - mu) * inv * g0 + bb0;
            s_ef[j*CZ + lane + 64] = (x1 - mu) * inv * g1 + bb1;
        }
    }
    __syncthreads();

    // ---------------- Phase B2: e2 = sig(ef@W_eg+b)*(ef@W_ep+b), og ----------
    {
        int z = tid & 127, jh = tid >> 7;
        float aEp[16], aEg[16], aOg[16];
        #pragma unroll
        for (int m = 0; m < 16; ++m) { aEp[m] = 0.f; aEg[m] = 0.f; aOg[m] = 0.f; }
        const float* efb = s_ef + jh*16*CZ;
        for (int c = 0; c < CZ; ++c) {
            float wep = W_ep[c*CZ + z];
            float weg = W_eg[c*CZ + z];
            float wog = W_og[c*CZ + z];
            const float* efc = efb + c;
            #pragma unroll
            for (int m = 0; m < 16; ++m) {
                float e = efc[m*CZ];
                aEp[m] = fmaf(e, wep, aEp[m]);
                aEg[m] = fmaf(e, weg, aEg[m]);
                aOg[m] = fmaf(e, wog, aOg[m]);
            }
        }
        float bep = b_ep[z], beg = b_eg[z], bog = b_og[z];
        #pragma unroll
        for (int m = 0; m < 16; ++m) {
            int j = jh*16 + m;
            s_e2[j][z] = sigmoidf_(aEg[m] + beg) * (aEp[m] + bep);
            s_og[j][z] = sigmoidf_(aOg[m] + bog);
        }
    }
    __syncthreads();   // s_ef dead; arena becomes taps/r0

    // ---------------- Phase C0: per-pair distance -> 8 RBF taps ---------------
    {
        const float spacing     = 20.0f / 63.0f;
        const float inv_spacing = 63.0f / 20.0f;
        const float inv_sigma   = 64.0f / 20.0f;   // 3.2
        #pragma unroll
        for (int q = 0; q < 4; ++q) {
            int p = q*256 + tid;
            int i = p >> 5, j = p & 31;
            float dx = s_t[j][0] - s_t[i][0] + 1e-8f;
            float dy = s_t[j][1] - s_t[i][1] + 1e-8f;
            float dz = s_t[j][2] - s_t[i][2] + 1e-8f;
            float D = sqrtf(dx*dx + dy*dy + dz*dz);
            int r0 = (int)floorf(D * inv_spacing) - 3;
            r0 = min(max(r0, 0), 56);
            s_r0[p] = r0;
            float tp[8];
            #pragma unroll
            for (int t = 0; t < 8; ++t) {
                float mu = (float)(r0 + t) * spacing;
                float d  = (D - mu) * inv_sigma;
                tp[t] = __expf(-d*d);
            }
            float4 ta = make_float4(tp[0], tp[1], tp[2], tp[3]);
            float4 tb = make_float4(tp[4], tp[5], tp[6], tp[7]);
            s_taps4[p*2 + 0] = ta;
            s_taps4[p*2 + 1] = tb;
        }
    }
    __syncthreads();

    // ---------------- Phase C1: upd_acc[i,z] = sum_j proj(i,j,z)*e2[j,z] ------
    float acc[16];
    float e2sum = 0.f;
    {
        int z = tid & 127, ih = tid >> 7;
        #pragma unroll
        for (int m = 0; m < 16; ++m) acc[m] = 0.f;
        const float* wdp_z = W_dp + z;
        for (int j = 0; j < KK; ++j) {
            float e2j = s_e2[j][z];
            e2sum += e2j;
            #pragma unroll 4
            for (int m = 0; m < 16; ++m) {
                int i = ih + 2*m;            // wave-uniform
                int p = (i << 5) | j;
                int r0 = s_r0[p];
                float4 ta = s_taps4[p*2 + 0];
                float4 tb = s_taps4[p*2 + 1];
                const float* w = wdp_z + (r0 << 7);
                float proj;
                proj = ta.x * w[0*CZ];
                proj = fmaf(ta.y, w[1*CZ], proj);
                proj = fmaf(ta.z, w[2*CZ], proj);
                proj = fmaf(ta.w, w[3*CZ], proj);
                proj = fmaf(tb.x, w[4*CZ], proj);
                proj = fmaf(tb.y, w[5*CZ], proj);
                proj = fmaf(tb.z, w[6*CZ], proj);
                proj = fmaf(tb.w, w[7*CZ], proj);
                acc[m] = fmaf(proj, e2j, acc[m]);
            }
        }
    }
    __syncthreads();   // taps dead; arena becomes s_upd

    // ---------------- Phase D0: apply b_dp term + gate3, stage to LDS ---------
    {
        int z = tid & 127, ih = tid >> 7;
        float bdp = b_dp[z];
        float g3  = s_gate3[z];
        #pragma unroll
        for (int m = 0; m < 16; ++m) {
            int i = ih + 2*m;
            s_upd[i*CZ + z] = g3 * (acc[m] + bdp * e2sum);
        }
    }
    __syncthreads();

    // ---------------- Phase D1: LayerNorm rows of upd -------------------------
    {
        float g0 = lno_g[lane], g1 = lno_g[lane + 64];
        float bb0 = lno_b[lane], bb1 = lno_b[lane + 64];
        for (int it = 0; it < 8; ++it) {
            int i = it*4 + wave;
            float x0 = s_upd[i*CZ + lane], x1 = s_upd[i*CZ + lane + 64];
            float s = x0 + x1, s2 = x0*x0 + x1*x1;
            #pragma unroll
            for (int o = 1; o < 64; o <<= 1) { s += __shfl_xor(s, o); s2 += __shfl_xor(s2, o); }
            float mu  = s * (1.f/128.f);
            float var = s2 * (1.f/128.f) - mu*mu;
            float inv = rsqrtf(var + 1e-5f);
            s_upd[i*CZ + lane]      = (x0 - mu) * inv * g0 + bb0;
            s_upd[i*CZ + lane + 64] = (x1 - mu) * inv * g1 + bb1;
        }
    }
    __syncthreads();

    // ---------------- Phase D2: (@ W_lo + b_lo) * og -> out -------------------
    {
        int z = tid & 127, jh = tid >> 7;
        float a2[16];
        #pragma unroll
        for (int m = 0; m < 16; ++m) a2[m] = 0.f;
        const float* ub = s_upd + jh*16*CZ;
        for (int c = 0; c < CZ; ++c) {
            float w = W_lo[c*CZ + z];
            const float* uc = ub + c;
            #pragma unroll
            for (int m = 0; m < 16; ++m) a2[m] = fmaf(uc[m*CZ], w, a2[m]);
        }
        float bl = b_lo[z];
        #pragma unroll
        for (int m = 0; m < 16; ++m) {
            int i = jh*16 + m;
            out[(ebase + i)*CZ + z] = (a2[m] + bl) * s_og[i][z];
        }
    }
}

extern "C" void kernel_launch(void* const* d_in, const int* in_sizes, int n_in,
                              void* d_out, int out_size, void* d_ws, size_t ws_size,
                              hipStream_t stream) {
    const float* nf    = (const float*)d_in[0];
    const float* ntr   = (const float*)d_in[1];
    const float* efeat = (const float*)d_in[2];
    const int*   eidx  = (const int*)  d_in[3];
    const float* W_nl  = (const float*)d_in[4];
    const float* b_nl  = (const float*)d_in[5];
    const float* W_nr  = (const float*)d_in[6];
    const float* b_nr  = (const float*)d_in[7];
    const float* ln_g  = (const float*)d_in[8];
    const float* ln_b  = (const float*)d_in[9];
    const float* W_ep  = (const float*)d_in[10];
    const float* b_ep  = (const float*)d_in[11];
    const float* W_eg  = (const float*)d_in[12];
    const float* b_eg  = (const float*)d_in[13];
    const float* W_dg  = (const float*)d_in[14];
    const float* b_dg  = (const float*)d_in[15];
    const float* W_dp  = (const float*)d_in[16];
    const float* b_dp  = (const float*)d_in[17];
    const float* lno_g = (const float*)d_in[18];
    const float* lno_b = (const float*)d_in[19];
    const float* W_lo  = (const float*)d_in[20];
    const float* b_lo  = (const float*)d_in[21];
    const float* W_og  = (const float*)d_in[22];
    const float* b_og  = (const float*)d_in[23];
    float* out = (float*)d_out;

    ntmu_kernel<<<NN, 256, 0, stream>>>(
        nf, ntr, efeat, eidx,
        W_nl, b_nl, W_nr, b_nr, ln_g, ln_b,
        W_ep, b_ep, W_eg, b_eg, W_dg, b_dg, W_dp, b_dp,
        lno_g, lno_b, W_lo, b_lo, W_og, b_og, out);
}

// Round 2
// 67.727 us; speedup vs baseline: 3.4543x; 3.4543x over previous
//
#include <hip/hip_runtime.h>

#define NN 1024
#define KK 32
#define CZ 128
#define CS 384
#define CG 16
#define NR 64

typedef __attribute__((ext_vector_type(8)))  _Float16 f16x8;
typedef __attribute__((ext_vector_type(16))) float    f32x16;

__device__ __forceinline__ float sigmoidf_(float x) { return 1.0f / (1.0f + __expf(-x)); }

__device__ __forceinline__ unsigned short h_bits(float f) {
    _Float16 h = (_Float16)f;
    return __builtin_bit_cast(unsigned short, h);
}
__device__ __forceinline__ float h2f_bits(unsigned short b) {
    return (float)__builtin_bit_cast(_Float16, b);
}

__launch_bounds__(256, 2)
__global__ void ntmu_kernel(
    const float* __restrict__ nf,    // [N,384]
    const float* __restrict__ ntr,   // [N,3]
    const float* __restrict__ efeat, // [E,128]
    const int*   __restrict__ eidx,  // [2,E]
    const float* __restrict__ W_nl, const float* __restrict__ b_nl,
    const float* __restrict__ W_nr, const float* __restrict__ b_nr,
    const float* __restrict__ ln_g, const float* __restrict__ ln_b,
    const float* __restrict__ W_ep, const float* __restrict__ b_ep,
    const float* __restrict__ W_eg, const float* __restrict__ b_eg,
    const float* __restrict__ W_dg, const float* __restrict__ b_dg,
    const float* __restrict__ W_dp, const float* __restrict__ b_dp,
    const float* __restrict__ lno_g, const float* __restrict__ lno_b,
    const float* __restrict__ W_lo, const float* __restrict__ b_lo,
    const float* __restrict__ W_og, const float* __restrict__ b_og,
    float* __restrict__ out)
{
    const int n    = blockIdx.x;
    const int tid  = threadIdx.x;
    const int lane = tid & 63;
    const int wave = tid >> 6;
    const int hi   = lane >> 5;           // 0/1 half of wave
    const int zt   = wave * 32;           // wave's 32-col z tile
    const int zc   = zt + (lane & 31);    // this lane's z column
    const int ebase = n * KK;

    __shared__ float s_e2 [KK*CZ];        // 16 KB f32
    __shared__ float s_upd[KK*CZ];        // 16 KB f32
    __shared__ short s_og [KK*CZ];        // 8 KB f16 bits
    __shared__ short s_ef [KK*CZ];        // 8 KB f16, XOR-swizzled, row stride 256B
    __shared__ short s_updb[KK*CZ];       // 8 KB f16, XOR-swizzled
    __shared__ __align__(16) short s_T[4*KK*NR]; // 16 KB f16 taps, swizzled, row stride 128B
    __shared__ float s_t[KK][4];
    __shared__ float s_gate3[CZ];
    __shared__ float s_nl[CG], s_nr[CG];
    __shared__ float s_pp[2][CZ];

    // ---------------- A0: gather destination coordinates ----------------
    if (tid < KK) {
        int d = eidx[NN*KK + ebase + tid];
        s_t[tid][0] = ntr[d*3 + 0];
        s_t[tid][1] = ntr[d*3 + 1];
        s_t[tid][2] = ntr[d*3 + 2];
    }
    // ---------------- A1: nl, nr node projections ------------------------
    if (wave < 2) {
        const float* W  = (wave == 0) ? W_nl : W_nr;
        const float* bb = (wave == 0) ? b_nl : b_nr;
        int g = lane >> 2, q = lane & 3;
        const float* x = nf + n * CS;
        float s = 0.f;
        int c0 = q * 96;
        for (int c = c0; c < c0 + 96; ++c) s = fmaf(x[c], W[c*CG + g], s);
        s += __shfl_xor(s, 1);
        s += __shfl_xor(s, 2);
        if (q == 0) { if (wave == 0) s_nl[g] = s + bb[g]; else s_nr[g] = s + bb[g]; }
    }
    __syncthreads();

    // ---------------- A2: gate3 partial (VALU; W_dg streamed from L2) ----
    {
        int z = tid & 127, h = tid >> 7;
        float p = 0.f;
        for (int a = h*8; a < h*8 + 8; ++a) {
            float nla = s_nl[a];
            #pragma unroll
            for (int b = 0; b < 16; ++b)
                p = fmaf(nla * s_nr[b], W_dg[(a*16 + b)*CZ + z], p);
        }
        s_pp[h][z] = p;
    }

    // ---------------- B1: LayerNorm(edge_features) -> s_ef (f16, swz) ----
    {
        float g0 = ln_g[lane], g1 = ln_g[lane + 64];
        float bb0 = ln_b[lane], bb1 = ln_b[lane + 64];
        for (int it = 0; it < 8; ++it) {
            int j = it*4 + wave;
            const float* row = efeat + (ebase + j) * CZ;
            float x0 = row[lane], x1 = row[lane + 64];
            float s = x0 + x1, s2 = x0*x0 + x1*x1;
            #pragma unroll
            for (int o = 1; o < 64; o <<= 1) { s += __shfl_xor(s, o); s2 += __shfl_xor(s2, o); }
            float mu  = s * (1.f/128.f);
            float inv = rsqrtf(s2 * (1.f/128.f) - mu*mu + 1e-5f);
            float y0 = (x0 - mu) * inv * g0 + bb0;
            float y1 = (x1 - mu) * inv * g1 + bb1;
            int swz = (j & 7) << 4;
            *(short*)((char*)s_ef + ((j*256 + lane*2)        ^ swz)) = (short)h_bits(y0);
            *(short*)((char*)s_ef + ((j*256 + (lane+64)*2)   ^ swz)) = (short)h_bits(y1);
        }
    }
    __syncthreads();

    // gate3 finalize
    if (tid < CZ) s_gate3[tid] = sigmoidf_(s_pp[0][tid] + s_pp[1][tid] + b_dg[tid]);

    // ---------------- B2: three GEMMs ef@{W_ep,W_eg,W_og} via MFMA -------
    f32x16 aEp, aEg, aOg;
    #pragma unroll
    for (int r = 0; r < 16; ++r) { aEp[r] = 0.f; aEg[r] = 0.f; aOg[r] = 0.f; }
    {
        const int arow = lane & 31;
        const int aswz = (arow & 7) << 4;
        for (int ks = 0; ks < 8; ++ks) {
            int abyte = (arow*256 + ks*32 + hi*16) ^ aswz;
            f16x8 af = *reinterpret_cast<const f16x8*>((const char*)s_ef + abyte);
            int c0 = ks*16 + hi*8;
            const float* pep = W_ep + c0*CZ + zc;
            const float* peg = W_eg + c0*CZ + zc;
            const float* pog = W_og + c0*CZ + zc;
            f16x8 bep, beg, bog;
            #pragma unroll
            for (int t = 0; t < 8; ++t) {
                bep[t] = (_Float16)pep[t*CZ];
                beg[t] = (_Float16)peg[t*CZ];
                bog[t] = (_Float16)pog[t*CZ];
            }
            aEp = __builtin_amdgcn_mfma_f32_32x32x16_f16(af, bep, aEp, 0, 0, 0);
            aEg = __builtin_amdgcn_mfma_f32_32x32x16_f16(af, beg, aEg, 0, 0, 0);
            aOg = __builtin_amdgcn_mfma_f32_32x32x16_f16(af, bog, aOg, 0, 0, 0);
        }
    }
    // epilogue: e2 = sig(eg)*(ep), og = sig(og); e2sum over j
    float esum = 0.f;
    {
        float bep = b_ep[zc], beg = b_eg[zc], bogc = b_og[zc];
        #pragma unroll
        for (int r = 0; r < 16; ++r) {
            int j = (r & 3) + 8*(r >> 2) + 4*hi;
            float e2v = sigmoidf_(aEg[r] + beg) * (aEp[r] + bep);
            s_e2[j*CZ + zc] = e2v;
            esum += e2v;
            s_og[j*CZ + zc] = (short)h_bits(sigmoidf_(aOg[r] + bogc));
        }
        esum += __shfl_xor(esum, 32);
    }

    // ---------------- W_dp B-fragments (held in registers) ---------------
    f16x8 wdp[4];
    #pragma unroll
    for (int ks = 0; ks < 4; ++ks) {
        int c0 = ks*16 + hi*8;
        const float* p = W_dp + c0*CZ + zc;
        #pragma unroll
        for (int t = 0; t < 8; ++t) wdp[ks][t] = (_Float16)p[t*CZ];
    }
    __syncthreads();
    const float g3  = s_gate3[zc];
    const float bdp = b_dp[zc];

    // ---------------- C: per 4-i chunk: taps fill + MFMA + contraction ----
    const float spacing     = 20.0f / 63.0f;
    const float inv_spacing = 63.0f / 20.0f;
    const float inv_sigma   = 64.0f / 20.0f;   // 3.2
    for (int ch = 0; ch < 8; ++ch) {
        __syncthreads();   // previous chunk's T reads complete
        if (tid < 128) {
            int il = tid >> 5, j = tid & 31;
            int i  = ch*4 + il;
            float dx = s_t[j][0] - s_t[i][0] + 1e-8f;
            float dy = s_t[j][1] - s_t[i][1] + 1e-8f;
            float dz = s_t[j][2] - s_t[i][2] + 1e-8f;
            float D  = sqrtf(dx*dx + dy*dy + dz*dz);
            int idx = (int)(D * inv_spacing);
            int r0  = min(max((idx - 3) & ~1, 0), 56);
            int rowbyte = (il*KK + j) * 128;
            int swz = (j & 7) << 4;
            int4 zz; zz.x = 0; zz.y = 0; zz.z = 0; zz.w = 0;
            #pragma unroll
            for (int o = 0; o < 8; ++o)
                *reinterpret_cast<int4*>((char*)s_T + ((rowbyte + o*16) ^ swz)) = zz;
            #pragma unroll
            for (int w = 0; w < 4; ++w) {
                float mu0 = (float)(r0 + 2*w)     * spacing;
                float mu1 = (float)(r0 + 2*w + 1) * spacing;
                float d0 = (D - mu0) * inv_sigma;
                float d1 = (D - mu1) * inv_sigma;
                unsigned pk = (unsigned)h_bits(__expf(-d0*d0))
                            | ((unsigned)h_bits(__expf(-d1*d1)) << 16);
                *reinterpret_cast<unsigned*>((char*)s_T + ((rowbyte + r0*2 + w*4) ^ swz)) = pk;
            }
        }
        __syncthreads();
        const int arow = lane & 31;
        const int aswz = (arow & 7) << 4;
        #pragma unroll
        for (int il = 0; il < 4; ++il) {
            f32x16 acc;
            #pragma unroll
            for (int r = 0; r < 16; ++r) acc[r] = 0.f;
            int abase = (il*KK + arow) * 128 + hi*16;
            #pragma unroll
            for (int ks = 0; ks < 4; ++ks) {
                f16x8 af = *reinterpret_cast<const f16x8*>((const char*)s_T + ((abase + ks*32) ^ aswz));
                acc = __builtin_amdgcn_mfma_f32_32x32x16_f16(af, wdp[ks], acc, 0, 0, 0);
            }
            float sum = 0.f;
            #pragma unroll
            for (int r = 0; r < 16; ++r) {
                int j = (r & 3) + 8*(r >> 2) + 4*hi;
                sum = fmaf(acc[r], s_e2[j*CZ + zc], sum);
            }
            sum += __shfl_xor(sum, 32);
            if (lane < 32) s_upd[(ch*4 + il)*CZ + zc] = g3 * (sum + bdp * esum);
        }
    }
    __syncthreads();

    // ---------------- D1: LayerNorm rows of upd -> s_updb (f16, swz) -----
    {
        float g0 = lno_g[lane], g1 = lno_g[lane + 64];
        float bb0 = lno_b[lane], bb1 = lno_b[lane + 64];
        for (int it = 0; it < 8; ++it) {
            int i = it*4 + wave;
            float x0 = s_upd[i*CZ + lane], x1 = s_upd[i*CZ + lane + 64];
            float s = x0 + x1, s2 = x0*x0 + x1*x1;
            #pragma unroll
            for (int o = 1; o < 64; o <<= 1) { s += __shfl_xor(s, o); s2 += __shfl_xor(s2, o); }
            float mu  = s * (1.f/128.f);
            float inv = rsqrtf(s2 * (1.f/128.f) - mu*mu + 1e-5f);
            float y0 = (x0 - mu) * inv * g0 + bb0;
            float y1 = (x1 - mu) * inv * g1 + bb1;
            int swz = (i & 7) << 4;
            *(short*)((char*)s_updb + ((i*256 + lane*2)      ^ swz)) = (short)h_bits(y0);
            *(short*)((char*)s_updb + ((i*256 + (lane+64)*2) ^ swz)) = (short)h_bits(y1);
        }
    }
    __syncthreads();

    // ---------------- D2: ln(upd) @ W_lo + b_lo, * og -> out -------------
    {
        f32x16 aLo;
        #pragma unroll
        for (int r = 0; r < 16; ++r) aLo[r] = 0.f;
        const int arow = lane & 31;
        const int aswz = (arow & 7) << 4;
        for (int ks = 0; ks < 8; ++ks) {
            int abyte = (arow*256 + ks*32 + hi*16) ^ aswz;
            f16x8 af = *reinterpret_cast<const f16x8*>((const char*)s_updb + abyte);
            int c0 = ks*16 + hi*8;
            const float* plo = W_lo + c0*CZ + zc;
            f16x8 blo;
            #pragma unroll
            for (int t = 0; t < 8; ++t) blo[t] = (_Float16)plo[t*CZ];
            aLo = __builtin_amdgcn_mfma_f32_32x32x16_f16(af, blo, aLo, 0, 0, 0);
        }
        float bl = b_lo[zc];
        #pragma unroll
        for (int r = 0; r < 16; ++r) {
            int j = (r & 3) + 8*(r >> 2) + 4*hi;
            float og = h2f_bits((unsigned short)s_og[j*CZ + zc]);
            out[(ebase + j)*CZ + zc] = (aLo[r] + bl) * og;
        }
    }
}

extern "C" void kernel_launch(void* const* d_in, const int* in_sizes, int n_in,
                              void* d_out, int out_size, void* d_ws, size_t ws_size,
                              hipStream_t stream) {
    const float* nf    = (const float*)d_in[0];
    const float* ntr   = (const float*)d_in[1];
    const float* efeat = (const float*)d_in[2];
    const int*   eidx  = (const int*)  d_in[3];
    const float* W_nl  = (const float*)d_in[4];
    const float* b_nl  = (const float*)d_in[5];
    const float* W_nr  = (const float*)d_in[6];
    const float* b_nr  = (const float*)d_in[7];
    const float* ln_g  = (const float*)d_in[8];
    const float* ln_b  = (const float*)d_in[9];
    const float* W_ep  = (const float*)d_in[10];
    const float* b_ep  = (const float*)d_in[11];
    const float* W_eg  = (const float*)d_in[12];
    const float* b_eg  = (const float*)d_in[13];
    const float* W_dg  = (const float*)d_in[14];
    const float* b_dg  = (const float*)d_in[15];
    const float* W_dp  = (const float*)d_in[16];
    const float* b_dp  = (const float*)d_in[17];
    const float* lno_g = (const float*)d_in[18];
    const float* lno_b = (const float*)d_in[19];
    const float* W_lo  = (const float*)d_in[20];
    const float* b_lo  = (const float*)d_in[21];
    const float* W_og  = (const float*)d_in[22];
    const float* b_og  = (const float*)d_in[23];
    float* out = (float*)d_out;

    ntmu_kernel<<<NN, 256, 0, stream>>>(
        nf, ntr, efeat, eidx,
        W_nl, b_nl, W_nr, b_nr, ln_g, ln_b,
        W_ep, b_ep, W_eg, b_eg, W_dg, b_dg, W_dp, b_dp,
        lno_g, lno_b, W_lo, b_lo, W_og, b_og, out);
}

// Round 3
// 66.285 us; speedup vs baseline: 3.5295x; 1.0217x over previous
//
#include <hip/hip_runtime.h>

#define NN 1024
#define KK 32
#define CZ 128
#define CS 384
#define CG 16
#define NR 64

typedef __attribute__((ext_vector_type(8)))  _Float16 f16x8;
typedef __attribute__((ext_vector_type(16))) float    f32x16;

// d_ws layout (f16 element offsets): transposed f16 weights Wt[z][k] = W[k][z]
#define WS_EP 0
#define WS_EG 16384
#define WS_OG 32768
#define WS_LO 49152
#define WS_DP 65536   // [128][64]
#define WS_NL 73728   // [16][384]
#define WS_NR 79872   // [16][384]
#define WS_TOT 86016

__device__ __forceinline__ float sigmoidf_(float x) { return 1.0f / (1.0f + __expf(-x)); }

__device__ __forceinline__ unsigned short h_bits(float f) {
    _Float16 h = (_Float16)f;
    return __builtin_bit_cast(unsigned short, h);
}
__device__ __forceinline__ float h2f_bits(unsigned short b) {
    return (float)__builtin_bit_cast(_Float16, b);
}

__global__ void convert_weights(
    const float* __restrict__ W_ep, const float* __restrict__ W_eg,
    const float* __restrict__ W_og, const float* __restrict__ W_lo,
    const float* __restrict__ W_dp, const float* __restrict__ W_nl,
    const float* __restrict__ W_nr, _Float16* __restrict__ ws)
{
    int t = blockIdx.x * 256 + threadIdx.x;
    if (t >= WS_TOT) return;
    float v;
    if (t < 65536) {
        const float* src = (t < 16384) ? W_ep : (t < 32768) ? W_eg : (t < 49152) ? W_og : W_lo;
        int tt = t & 16383;
        int z = tt >> 7, c = tt & 127;
        v = src[c*128 + z];
    } else if (t < 73728) {
        int tt = t - 65536;
        int z = tt >> 6, r = tt & 63;
        v = W_dp[r*128 + z];
    } else if (t < 79872) {
        int tt = t - 73728;
        int g = tt / 384, c = tt - g*384;
        v = W_nl[c*16 + g];
    } else {
        int tt = t - 79872;
        int g = tt / 384, c = tt - g*384;
        v = W_nr[c*16 + g];
    }
    ws[t] = (_Float16)v;
}

__launch_bounds__(256, 3)
__global__ void ntmu_kernel(
    const float* __restrict__ nf,    // [N,384]
    const float* __restrict__ ntr,   // [N,3]
    const float* __restrict__ efeat, // [E,128]
    const int*   __restrict__ eidx,  // [2,E]
    const float* __restrict__ W_dg,  // [256,128] f32 (kept)
    const float* __restrict__ b_dg,
    const float* __restrict__ ln_g,  const float* __restrict__ ln_b,
    const float* __restrict__ b_nl,  const float* __restrict__ b_nr,
    const float* __restrict__ b_ep,  const float* __restrict__ b_eg,
    const float* __restrict__ b_og,  const float* __restrict__ b_dp,
    const float* __restrict__ lno_g, const float* __restrict__ lno_b,
    const float* __restrict__ b_lo,
    const _Float16* __restrict__ ws,
    float* __restrict__ out)
{
    const int n    = blockIdx.x;
    const int tid  = threadIdx.x;
    const int lane = tid & 63;
    const int wave = tid >> 6;
    const int hi   = lane >> 5;
    const int zc   = wave * 32 + (lane & 31);
    const int arow = lane & 31;
    const int aswz = (arow & 7) << 4;
    const int ebase = n * KK;

    // LDS: arena (32KB; first 8KB doubles as s_ef) + upd (8KB f16) + misc
    __shared__ __align__(16) short s_arena[8*KK*NR]; // taps T: [8 i][32 j][64 r] f16, swizzled
    __shared__ short s_upd_h[KK*CZ];                 // f16; unswz after C, swz after D1
    __shared__ float s_t[KK][4];
    __shared__ float s_gate3[CZ];
    __shared__ float s_nl[CG], s_nr[CG];
    __shared__ float s_pp[2][CZ];

    short* s_ef = s_arena;   // [32 rows][128 f16] swizzled, dead after B2
    char*  s_T  = (char*)s_arena;

    // ---------------- A0: gather destination coordinates ----------------
    if (tid < KK) {
        int d = eidx[NN*KK + ebase + tid];
        s_t[tid][0] = ntr[d*3 + 0];
        s_t[tid][1] = ntr[d*3 + 1];
        s_t[tid][2] = ntr[d*3 + 2];
    }
    // ---------------- A1: nl, nr node projections (f16 Wt, vec loads) ----
    if (wave < 2) {
        int g = lane >> 2, q = lane & 3;
        const _Float16* Wt = ws + ((wave == 0) ? WS_NL : WS_NR) + g*384 + q*96;
        const float* x = nf + n * CS + q*96;
        float s = 0.f;
        #pragma unroll
        for (int c4 = 0; c4 < 96; c4 += 8) {
            f16x8 wv = *reinterpret_cast<const f16x8*>(Wt + c4);
            #pragma unroll
            for (int t = 0; t < 8; ++t) s = fmaf(x[c4 + t], (float)wv[t], s);
        }
        s += __shfl_xor(s, 1);
        s += __shfl_xor(s, 2);
        if (q == 0) {
            if (wave == 0) s_nl[g] = s + b_nl[g];
            else           s_nr[g] = s + b_nr[g];
        }
    }
    __syncthreads();

    // ---------------- A2: gate3 partials (W_dg f32 from L2) --------------
    {
        int z = tid & 127, h = tid >> 7;
        float p = 0.f;
        #pragma unroll 2
        for (int a = h*8; a < h*8 + 8; ++a) {
            float nla = s_nl[a];
            #pragma unroll
            for (int b = 0; b < 16; ++b)
                p = fmaf(nla * s_nr[b], W_dg[(a*16 + b)*CZ + z], p);
        }
        s_pp[h][z] = p;
    }

    // ---------------- B1: LayerNorm(edge_features) -> s_ef (f16, swz) ----
    {
        float g0 = ln_g[lane], g1 = ln_g[lane + 64];
        float bb0 = ln_b[lane], bb1 = ln_b[lane + 64];
        for (int it = 0; it < 8; ++it) {
            int j = it*4 + wave;
            const float* row = efeat + (ebase + j) * CZ;
            float x0 = row[lane], x1 = row[lane + 64];
            float s = x0 + x1, s2 = x0*x0 + x1*x1;
            #pragma unroll
            for (int o = 1; o < 64; o <<= 1) { s += __shfl_xor(s, o); s2 += __shfl_xor(s2, o); }
            float mu  = s * (1.f/128.f);
            float inv = rsqrtf(s2 * (1.f/128.f) - mu*mu + 1e-5f);
            float y0 = (x0 - mu) * inv * g0 + bb0;
            float y1 = (x1 - mu) * inv * g1 + bb1;
            int swz = (j & 7) << 4;
            *(short*)((char*)s_ef + ((j*256 + lane*2)      ^ swz)) = (short)h_bits(y0);
            *(short*)((char*)s_ef + ((j*256 + (lane+64)*2) ^ swz)) = (short)h_bits(y1);
        }
    }
    __syncthreads();

    // gate3 finalize
    if (tid < CZ) s_gate3[tid] = sigmoidf_(s_pp[0][tid] + s_pp[1][tid] + b_dg[tid]);

    // ---------------- B2: ef @ {W_ep,W_eg,W_og} via MFMA -----------------
    f32x16 aEp, aEg, aOg;
    #pragma unroll
    for (int r = 0; r < 16; ++r) { aEp[r] = 0.f; aEg[r] = 0.f; aOg[r] = 0.f; }
    {
        const _Float16* wep = ws + WS_EP + zc*128;
        const _Float16* weg = ws + WS_EG + zc*128;
        const _Float16* wog = ws + WS_OG + zc*128;
        #pragma unroll
        for (int ks = 0; ks < 8; ++ks) {
            int abyte = (arow*256 + ks*32 + hi*16) ^ aswz;
            f16x8 af = *reinterpret_cast<const f16x8*>((const char*)s_ef + abyte);
            int kof = ks*16 + hi*8;
            f16x8 bep = *reinterpret_cast<const f16x8*>(wep + kof);
            f16x8 beg = *reinterpret_cast<const f16x8*>(weg + kof);
            f16x8 bog = *reinterpret_cast<const f16x8*>(wog + kof);
            aEp = __builtin_amdgcn_mfma_f32_32x32x16_f16(af, bep, aEp, 0, 0, 0);
            aEg = __builtin_amdgcn_mfma_f32_32x32x16_f16(af, beg, aEg, 0, 0, 0);
            aOg = __builtin_amdgcn_mfma_f32_32x32x16_f16(af, bog, aOg, 0, 0, 0);
        }
    }
    // epilogue: e2, og, esum all stay in REGISTERS (C/D layout matches C-phase needs)
    float e2v[16], og_r[16];
    float esum = 0.f;
    {
        float bep = b_ep[zc], beg = b_eg[zc], bogc = b_og[zc];
        #pragma unroll
        for (int r = 0; r < 16; ++r) {
            float v = sigmoidf_(aEg[r] + beg) * (aEp[r] + bep);
            e2v[r] = v;
            esum += v;
            og_r[r] = sigmoidf_(aOg[r] + bogc);
        }
        esum += __shfl_xor(esum, 32);
    }

    // W_dp B-fragments (4 x dwordx4 from transposed f16)
    f16x8 wdp[4];
    {
        const _Float16* wdpp = ws + WS_DP + zc*64;
        #pragma unroll
        for (int ks = 0; ks < 4; ++ks)
            wdp[ks] = *reinterpret_cast<const f16x8*>(wdpp + ks*16 + hi*8);
    }
    __syncthreads();   // s_ef dead; s_gate3 ready; arena becomes s_T
    const float g3  = s_gate3[zc];
    const float bdp = b_dp[zc];

    // ---------------- C: 4 chunks of 8 i-rows -----------------------------
    const float spacing     = 20.0f / 63.0f;
    const float inv_spacing = 63.0f / 20.0f;
    const float inv_sigma   = 64.0f / 20.0f;   // 3.2
    for (int ch = 0; ch < 4; ++ch) {
        // fill: one (i,j) pair per thread; rows wave-exclusive (no race)
        {
            int ilf = tid >> 5;            // 0..7
            int j   = tid & 31;
            int i   = ch*8 + ilf;
            float dx = s_t[j][0] - s_t[i][0] + 1e-8f;
            float dy = s_t[j][1] - s_t[i][1] + 1e-8f;
            float dz = s_t[j][2] - s_t[i][2] + 1e-8f;
            float D  = sqrtf(dx*dx + dy*dy + dz*dz);
            int idx = (int)(D * inv_spacing);
            int r0  = min(max((idx - 3) & ~1, 0), 56);
            int rowbyte = (ilf*KK + j) * 128;
            int swz = (j & 7) << 4;
            int4 zz; zz.x = 0; zz.y = 0; zz.z = 0; zz.w = 0;
            #pragma unroll
            for (int o = 0; o < 8; ++o)
                *reinterpret_cast<int4*>(s_T + ((rowbyte + o*16) ^ swz)) = zz;
            #pragma unroll
            for (int w = 0; w < 4; ++w) {
                float mu0 = (float)(r0 + 2*w) * spacing;
                float mu1 = mu0 + spacing;
                float d0 = (D - mu0) * inv_sigma;
                float d1 = (D - mu1) * inv_sigma;
                unsigned pk = (unsigned)h_bits(__expf(-d0*d0))
                            | ((unsigned)h_bits(__expf(-d1*d1)) << 16);
                *reinterpret_cast<unsigned*>(s_T + ((rowbyte + r0*2 + w*4) ^ swz)) = pk;
            }
        }
        __syncthreads();
        #pragma unroll
        for (int il = 0; il < 8; ++il) {
            f32x16 acc;
            #pragma unroll
            for (int r = 0; r < 16; ++r) acc[r] = 0.f;
            int abase = (il*KK + arow) * 128 + hi*16;
            #pragma unroll
            for (int ks = 0; ks < 4; ++ks) {
                f16x8 af = *reinterpret_cast<const f16x8*>(s_T + ((abase + ks*32) ^ aswz));
                acc = __builtin_amdgcn_mfma_f32_32x32x16_f16(af, wdp[ks], acc, 0, 0, 0);
            }
            float sum = 0.f;
            #pragma unroll
            for (int r = 0; r < 16; ++r) sum = fmaf(acc[r], e2v[r], sum);
            sum += __shfl_xor(sum, 32);
            if (lane < 32)
                s_upd_h[(ch*8 + il)*CZ + zc] = (short)h_bits(g3 * (sum + bdp * esum));
        }
        __syncthreads();
    }

    // ---------------- D1: LayerNorm rows of upd, in place (swz on write) --
    {
        float g0 = lno_g[lane], g1 = lno_g[lane + 64];
        float bb0 = lno_b[lane], bb1 = lno_b[lane + 64];
        for (int it = 0; it < 8; ++it) {
            int i = it*4 + wave;
            float x0 = h2f_bits((unsigned short)s_upd_h[i*CZ + lane]);
            float x1 = h2f_bits((unsigned short)s_upd_h[i*CZ + lane + 64]);
            float s = x0 + x1, s2 = x0*x0 + x1*x1;
            #pragma unroll
            for (int o = 1; o < 64; o <<= 1) { s += __shfl_xor(s, o); s2 += __shfl_xor(s2, o); }
            float mu  = s * (1.f/128.f);
            float inv = rsqrtf(s2 * (1.f/128.f) - mu*mu + 1e-5f);
            float y0 = (x0 - mu) * inv * g0 + bb0;
            float y1 = (x1 - mu) * inv * g1 + bb1;
            int swz = (i & 7) << 4;
            *(short*)((char*)s_upd_h + ((i*256 + lane*2)      ^ swz)) = (short)h_bits(y0);
            *(short*)((char*)s_upd_h + ((i*256 + (lane+64)*2) ^ swz)) = (short)h_bits(y1);
        }
    }
    __syncthreads();

    // ---------------- D2: ln(upd) @ W_lo + b_lo, * og -> out --------------
    {
        f32x16 aLo;
        #pragma unroll
        for (int r = 0; r < 16; ++r) aLo[r] = 0.f;
        const _Float16* wlo = ws + WS_LO + zc*128;
        #pragma unroll
        for (int ks = 0; ks < 8; ++ks) {
            int abyte = (arow*256 + ks*32 + hi*16) ^ aswz;
            f16x8 af = *reinterpret_cast<const f16x8*>((const char*)s_upd_h + abyte);
            f16x8 blo = *reinterpret_cast<const f16x8*>(wlo + ks*16 + hi*8);
            aLo = __builtin_amdgcn_mfma_f32_32x32x16_f16(af, blo, aLo, 0, 0, 0);
        }
        float bl = b_lo[zc];
        #pragma unroll
        for (int r = 0; r < 16; ++r) {
            int j = (r & 3) + 8*(r >> 2) + 4*hi;
            out[(ebase + j)*CZ + zc] = (aLo[r] + bl) * og_r[r];
        }
    }
}

extern "C" void kernel_launch(void* const* d_in, const int* in_sizes, int n_in,
                              void* d_out, int out_size, void* d_ws, size_t ws_size,
                              hipStream_t stream) {
    const float* nf    = (const float*)d_in[0];
    const float* ntr   = (const float*)d_in[1];
    const float* efeat = (const float*)d_in[2];
    const int*   eidx  = (const int*)  d_in[3];
    const float* W_nl  = (const float*)d_in[4];
    const float* b_nl  = (const float*)d_in[5];
    const float* W_nr  = (const float*)d_in[6];
    const float* b_nr  = (const float*)d_in[7];
    const float* ln_g  = (const float*)d_in[8];
    const float* ln_b  = (const float*)d_in[9];
    const float* W_ep  = (const float*)d_in[10];
    const float* b_ep  = (const float*)d_in[11];
    const float* W_eg  = (const float*)d_in[12];
    const float* b_eg  = (const float*)d_in[13];
    const float* W_dg  = (const float*)d_in[14];
    const float* b_dg  = (const float*)d_in[15];
    const float* W_dp  = (const float*)d_in[16];
    const float* b_dp  = (const float*)d_in[17];
    const float* lno_g = (const float*)d_in[18];
    const float* lno_b = (const float*)d_in[19];
    const float* W_lo  = (const float*)d_in[20];
    const float* b_lo  = (const float*)d_in[21];
    const float* W_og  = (const float*)d_in[22];
    const float* b_og  = (const float*)d_in[23];
    float* out = (float*)d_out;
    _Float16* ws = (_Float16*)d_ws;

    convert_weights<<<(WS_TOT + 255)/256, 256, 0, stream>>>(
        W_ep, W_eg, W_og, W_lo, W_dp, W_nl, W_nr, ws);

    ntmu_kernel<<<NN, 256, 0, stream>>>(
        nf, ntr, efeat, eidx,
        W_dg, b_dg, ln_g, ln_b, b_nl, b_nr,
        b_ep, b_eg, b_og, b_dp, lno_g, lno_b, b_lo,
        ws, out);
}